// Round 1
// baseline (659.614 us; speedup 1.0000x reference)
//
#include <hip/hip_runtime.h>
#include <math.h>

#define D 1024
#define V 16384
#define NROWS 8192
#define NCAND 128
#define DELTA 0.03f

typedef __bf16 bf16_t;
typedef bf16_t bf16x8 __attribute__((ext_vector_type(8)));
typedef float f32x4 __attribute__((ext_vector_type(4)));

__device__ __forceinline__ unsigned int sortable_key(float v) {
    unsigned int b = __float_as_uint(v);
    return (b & 0x80000000u) ? ~b : (b | 0x80000000u);
}
__device__ __forceinline__ float unkey(unsigned int key) {
    unsigned int b = (key & 0x80000000u) ? (key & 0x7FFFFFFFu) : ~key;
    return __uint_as_float(b);
}
__device__ __forceinline__ uint2 trunc4(float4 v) {
    unsigned int u0 = __float_as_uint(v.x), u1 = __float_as_uint(v.y);
    unsigned int u2 = __float_as_uint(v.z), u3 = __float_as_uint(v.w);
    uint2 hw;
    hw.x = (u0 >> 16) | (u1 & 0xFFFF0000u);
    hw.y = (u2 >> 16) | (u3 & 0xFFFF0000u);
    return hw;
}
__device__ __forceinline__ void split4(float4 v, uint2& hw, uint2& lw) {
    unsigned int u0 = __float_as_uint(v.x), u1 = __float_as_uint(v.y);
    unsigned int u2 = __float_as_uint(v.z), u3 = __float_as_uint(v.w);
    float l0 = v.x - __uint_as_float(u0 & 0xFFFF0000u);
    float l1 = v.y - __uint_as_float(u1 & 0xFFFF0000u);
    float l2 = v.z - __uint_as_float(u2 & 0xFFFF0000u);
    float l3 = v.w - __uint_as_float(u3 & 0xFFFF0000u);
    hw.x = (u0 >> 16) | (u1 & 0xFFFF0000u);
    hw.y = (u2 >> 16) | (u3 & 0xFFFF0000u);
    lw.x = (__float_as_uint(l0) >> 16) | (__float_as_uint(l1) & 0xFFFF0000u);
    lw.y = (__float_as_uint(l2) >> 16) | (__float_as_uint(l3) & 0xFFFF0000u);
}

// async 16B global->LDS copy (per-lane global addr, wave-uniform LDS base + lane*16)
__device__ __forceinline__ void gload16(const ushort* g, ushort* s) {
    __builtin_amdgcn_global_load_lds((const __attribute__((address_space(1))) void*)g,
                                     (__attribute__((address_space(3))) void*)s,
                                     16, 0, 0);
}

// ---------------- merged: row L2-norms of W and X + zero of packed/count ----------------
__global__ __launch_bounds__(256) void prep_kernel(const float* __restrict__ W,
                                                   const float* __restrict__ X,
                                                   float* __restrict__ RK,
                                                   float* __restrict__ RQ,
                                                   unsigned long long* __restrict__ packed,
                                                   unsigned int* __restrict__ count) {
    int tid = threadIdx.x;
    int row = blockIdx.x * 4 + (tid >> 6);
    int lane = tid & 63;
    const float* src;
    float* dst;
    if (row < V) { src = W + (size_t)row * D; dst = RK + row; }
    else { src = X + (size_t)(row - V) * D; dst = RQ + (row - V); }
    const float4* p = (const float4*)src;
    float ss = 0.f;
#pragma unroll
    for (int i = 0; i < 4; ++i) {
        float4 v = p[lane + 64 * i];
        ss += v.x * v.x + v.y * v.y + v.z * v.z + v.w * v.w;
    }
#pragma unroll
    for (int m = 32; m >= 1; m >>= 1) ss += __shfl_xor(ss, m, 64);
    if (lane == 0) {
        *dst = rsqrtf(fmaxf(ss, 1e-12f));
        if (row >= V) { packed[row - V] = 0ull; count[row - V] = 0u; }
    }
}

// ---------------- truncate rows of src into MFMA-fragment-packed bf16 ----------------
// dst[((t16*32 + kc)*64 + lane)*8 + j]: t16=row>>4, lane=(row&15)|((kk>>3)<<4), j=kk&7 (kk=k&31)
__global__ __launch_bounds__(256) void pack_kernel(const float* __restrict__ src,
                                                   ushort* __restrict__ dst) {
    int f = blockIdx.x * 256 + threadIdx.x;
    int row = f >> 8;
    int kq = f & 255;
    int k0 = kq * 4;
    float4 v = *((const float4*)(src + (size_t)row * D) + kq);
    uint2 hw = trunc4(v);
    int t16 = row >> 4, m = row & 15;
    int kc = k0 >> 5, kk = k0 & 31;
    int lane = m | ((kk >> 3) << 4);
    int j0 = kk & 4;
    int idx = ((t16 * 32 + kc) * 64 + lane) * 8 + j0;
    *(uint2*)(dst + idx) = hw;
}

// ---------------- approx sim GEMM: 256x256 LDS-staged tile, counted-vmcnt pipeline ----------------
// 8 waves (2M x 4N), per-wave 128x64 out. K-tile = 64 (2 kc frags). LDS = 2 x 64KB double buffer.
// Data is fragment-packed in global, so global_load_lds staging is linear (wave-uniform dest OK)
// and ds_read_b128 fragment reads are conflict-free with NO swizzle.
// Pipeline: compute kt from buf[kt&1]; s_barrier; stage kt+2 into buf[kt&1]; vmcnt(8)
// (waits for kt+1's loads, leaves kt+2's 8 loads in flight); s_barrier. Never drains in-loop.
__global__ __launch_bounds__(512, 2) void gemm1_kernel(const ushort* __restrict__ Xhi,
                                                       const ushort* __restrict__ Wfrag,
                                                       const float* __restrict__ RK,
                                                       unsigned long long* __restrict__ packed,
                                                       unsigned int* __restrict__ count,
                                                       ushort* __restrict__ candCol,
                                                       int colBase, int perX) {
    __shared__ __align__(16) unsigned char ldsraw[131072];
    ushort* lds = (ushort*)ldsraw;

    const int tid = threadIdx.x;
    const int l = tid & 63;
    const int w = tid >> 6;                 // 0..7
    const int wy = w >> 2, wx = w & 3;      // per-wave: rows wy*128.., cols wx*64..

    const int lin = blockIdx.x;
    const int x = lin & 7;                  // XCD
    const int j = lin >> 3;
    const int rt = j / perX;
    const int ctl = x * perX + (j - rt * perX);
    const int rowBase = rt * 256;
    const int cwLocal = ctl * 256;

    f32x4 acc[8][4];
#pragma unroll
    for (int mt = 0; mt < 8; ++mt)
#pragma unroll
        for (int nt = 0; nt < 4; ++nt) acc[mt][nt] = (f32x4)0.f;

    // staging role: waves 0-3 stage A (32 x 1KB frags), waves 4-7 stage B.
    // unit u = w*8+i: t16_local = u>>1 (== w*4 + (i>>1)), kc_in = u&1 (== i&1)
    const ushort* gs = (w < 4)
        ? (Xhi + (size_t)(rt * 16 + w * 4) * 16384 + l * 8)
        : (Wfrag + (size_t)(ctl * 16 + (w - 4) * 4) * 16384 + l * 8);
    const int ldsBaseU = w * 8 * 512;       // elem offset of this wave's 8 units

    auto stage = [&](int buf, int kt) {
#pragma unroll
        for (int i = 0; i < 8; ++i)
            gload16(gs + (size_t)kt * 1024 + (i >> 1) * 16384 + (i & 1) * 512,
                    lds + buf * 32768 + ldsBaseU + i * 512);
    };

    // prologue: tiles 0 and 1 in flight; wait only for tile 0 (8 newest stay outstanding)
    stage(0, 0);
    stage(1, 1);
    asm volatile("s_waitcnt vmcnt(8)" ::: "memory");
    __builtin_amdgcn_sched_barrier(0);
    __builtin_amdgcn_s_barrier();

    for (int kt = 0; kt < 16; ++kt) {
        const int base = (kt & 1) * 32768;
        // all B frags for this wave's 64 cols: nt 0..3 x kc 0..1
        bf16x8 bf[8];
#pragma unroll
        for (int nt = 0; nt < 4; ++nt)
#pragma unroll
            for (int kc = 0; kc < 2; ++kc)
                bf[nt * 2 + kc] = *(const bf16x8*)&lds[base + 16384 + ((wx * 4 + nt) * 2 + kc) * 512 + l * 8];
#pragma unroll
        for (int mh = 0; mh < 2; ++mh) {
            bf16x8 af[8];
#pragma unroll
            for (int mi = 0; mi < 4; ++mi)
#pragma unroll
                for (int kc = 0; kc < 2; ++kc)
                    af[mi * 2 + kc] = *(const bf16x8*)&lds[base + ((wy * 8 + mh * 4 + mi) * 2 + kc) * 512 + l * 8];
            __builtin_amdgcn_s_setprio(1);
#pragma unroll
            for (int nt = 0; nt < 4; ++nt)
#pragma unroll
                for (int mi = 0; mi < 4; ++mi) {
                    const int mt = mh * 4 + mi;
                    acc[mt][nt] = __builtin_amdgcn_mfma_f32_16x16x32_bf16(af[mi * 2 + 0], bf[nt * 2 + 0], acc[mt][nt], 0, 0, 0);
                    acc[mt][nt] = __builtin_amdgcn_mfma_f32_16x16x32_bf16(af[mi * 2 + 1], bf[nt * 2 + 1], acc[mt][nt], 0, 0, 0);
                }
            __builtin_amdgcn_s_setprio(0);
        }
        __builtin_amdgcn_s_barrier();           // all waves done reading buf[kt&1]
        if (kt + 2 < 16) {
            stage(kt & 1, kt + 2);              // 8 loads issued, stay in flight
            asm volatile("s_waitcnt vmcnt(8)" ::: "memory");   // tile kt+1 landed
        } else {
            asm volatile("s_waitcnt vmcnt(0)" ::: "memory");   // tail drain
        }
        __builtin_amdgcn_sched_barrier(0);
        __builtin_amdgcn_s_barrier();           // all waves' kt+1 data visible
    }

    // ---- epilogue stage 1: block-level per-row max -> global running max ----
    // staging buffers dead; overlay reduction arrays on LDS.
    unsigned long long (*red)[4] = (unsigned long long (*)[4])ldsraw;   // 256 x 4 x 8B = 8KB
    float* gthr = (float*)(ldsraw + 16384);                             // 1KB @ 16KB

    const int q = l >> 4, c = l & 15;
    float rk_l[4];
#pragma unroll
    for (int nt = 0; nt < 4; ++nt) rk_l[nt] = RK[colBase + cwLocal + wx * 64 + nt * 16 + c];
#pragma unroll
    for (int mt = 0; mt < 8; ++mt) {
#pragma unroll
        for (int r = 0; r < 4; ++r) {
            unsigned long long pk = 0;
#pragma unroll
            for (int nt = 0; nt < 4; ++nt) {
                float v = acc[mt][nt][r] * rk_l[nt];
                int col = colBase + cwLocal + wx * 64 + nt * 16 + c;
                unsigned long long p = ((unsigned long long)sortable_key(v) << 32) |
                                       (unsigned long long)(~(unsigned int)col);
                if (p > pk) pk = p;
            }
#pragma unroll
            for (int m = 1; m < 16; m <<= 1) {
                unsigned long long o = __shfl_xor(pk, m, 64);
                if (o > pk) pk = o;
            }
            if (c == 0) red[wy * 128 + mt * 16 + q * 4 + r][wx] = pk;
        }
    }
    __syncthreads();
    if (tid < 256) {
        unsigned long long a = red[tid][0];
#pragma unroll
        for (int i = 1; i < 4; ++i) { unsigned long long bb = red[tid][i]; if (bb > a) a = bb; }
        unsigned long long old = atomicMax(packed + (rowBase + tid), a);
        unsigned long long g = (old > a) ? old : a;
        gthr[tid] = unkey((unsigned int)(g >> 32)) - DELTA;
    }
    __syncthreads();
    // ---- epilogue stage 2: append candidates within DELTA of known running max ----
#pragma unroll
    for (int mt = 0; mt < 8; ++mt) {
#pragma unroll
        for (int r = 0; r < 4; ++r) {
            int lrow = wy * 128 + mt * 16 + q * 4 + r;
            float thr = gthr[lrow];
            int grow = rowBase + lrow;
#pragma unroll
            for (int nt = 0; nt < 4; ++nt) {
                float v = acc[mt][nt][r] * rk_l[nt];
                if (v >= thr) {
                    unsigned int slot = atomicAdd(count + grow, 1u);
                    if (slot < NCAND) {
                        int col = colBase + cwLocal + wx * 64 + nt * 16 + c;
                        candCol[(size_t)grow * NCAND + slot] = (ushort)col;
                    }
                }
            }
        }
    }
}

// ---------------- exact fp32 rescore + LN stats (merged) ----------------
__global__ __launch_bounds__(256) void rescore_kernel(const float* __restrict__ X,
                                                      const float* __restrict__ W,
                                                      const float* __restrict__ RK,
                                                      const float* __restrict__ RQ,
                                                      const unsigned int* __restrict__ count,
                                                      const ushort* __restrict__ candCol,
                                                      float* __restrict__ outIdx,
                                                      float* __restrict__ outSim,
                                                      int* __restrict__ idxArr,
                                                      float* __restrict__ MU,
                                                      float* __restrict__ RS) {
    int wave = threadIdx.x >> 6, l = threadIdx.x & 63;
    int row = blockIdx.x * 4 + wave;
    unsigned int n = count[row];
    if (n > NCAND) n = NCAND;
    const float4* X4 = (const float4*)X + (size_t)row * 256;
    unsigned long long best = 0;
    for (unsigned int i = 0; i < n; ++i) {
        int col = (int)candCol[(size_t)row * NCAND + i];
        const float4* W4 = (const float4*)W + (size_t)col * 256;
        float s = 0.f;
#pragma unroll
        for (int jj = 0; jj < 4; ++jj) {
            float4 a = X4[jj * 64 + l];
            float4 b = W4[jj * 64 + l];
            s += a.x * b.x + a.y * b.y + a.z * b.z + a.w * b.w;
        }
#pragma unroll
        for (int m = 32; m >= 1; m >>= 1) s += __shfl_xor(s, m, 64);
        float v = s * RK[col];
        unsigned long long pk = ((unsigned long long)sortable_key(v) << 32) |
                                (unsigned long long)(~(unsigned int)col);
        if (pk > best) best = pk;
    }
    int idx = (int)(~(unsigned int)(best & 0xFFFFFFFFull)) & 0xFFFF;
    const float4* Z4 = (const float4*)W + (size_t)idx * 256;
    float s = 0.f, s2 = 0.f;
#pragma unroll
    for (int jj = 0; jj < 4; ++jj) {
        float4 a = X4[jj * 64 + l];
        float4 z = Z4[jj * 64 + l];
        float4 e;
        e.x = (z.x - a.x) + a.x;
        e.y = (z.y - a.y) + a.y;
        e.z = (z.z - a.z) + a.z;
        e.w = (z.w - a.w) + a.w;
        s  += e.x + e.y + e.z + e.w;
        s2 += e.x * e.x + e.y * e.y + e.z * e.z + e.w * e.w;
    }
#pragma unroll
    for (int m = 32; m >= 1; m >>= 1) {
        s  += __shfl_xor(s, m, 64);
        s2 += __shfl_xor(s2, m, 64);
    }
    if (l == 0) {
        outIdx[row] = (float)idx;
        outSim[row] = unkey((unsigned int)(best >> 32)) * RQ[row];
        idxArr[row] = idx;
        float mean = s * (1.f / D);
        float var  = s2 * (1.f / D) - mean * mean;
        MU[row] = mean;
        RS[row] = rsqrtf(var + 1e-6f);
    }
}

// ---------------- projection GEMM: bf16 3-pass MFMA, LN fused into A staging ----------------
__global__ __launch_bounds__(256, 2) void gemm2_kernel(const float* __restrict__ X,
                                                       const float* __restrict__ W,
                                                       const int* __restrict__ idxArr,
                                                       const float* __restrict__ MU,
                                                       const float* __restrict__ RS,
                                                       const float* __restrict__ gamma,
                                                       const float* __restrict__ beta,
                                                       const float* __restrict__ B,
                                                       float* __restrict__ Out) {
    __shared__ ushort Ah[2][8][64][8];
    __shared__ ushort Al[2][8][64][8];
    __shared__ ushort Bh2[2][8][64][8];
    __shared__ ushort Bl2[2][8][64][8];
    __shared__ float Gs[1024];
    __shared__ float Bt[1024];

    const int tid = threadIdx.x;
    const int l = tid & 63;
    const int wave = tid >> 6;
    const int wy = wave >> 1, wx = wave & 1;
    const int rowBase = blockIdx.y * 128;
    const int nBase   = blockIdx.x * 128;

    *(float4*)&Gs[tid * 4] = *(const float4*)(gamma + tid * 4);
    *(float4*)&Bt[tid * 4] = *(const float4*)(beta + tid * 4);

    f32x4 acc[4][4];
#pragma unroll
    for (int mt = 0; mt < 4; ++mt)
#pragma unroll
        for (int nt = 0; nt < 4; ++nt) acc[mt][nt] = (f32x4)0.f;

    const int srow = tid >> 3, skq = tid & 7;
    const int sn = tid & 127, sdq = tid >> 7;
    int aidx[4];
    float amu[4], ars[4];
#pragma unroll
    for (int i = 0; i < 4; ++i) {
        int grow = rowBase + srow + i * 32;
        aidx[i] = idxArr[grow];
        amu[i] = MU[grow];
        ars[i] = RS[grow];
    }

    __syncthreads();

    float4 pz[4], pxv[4], pbv[4];
#pragma unroll
    for (int i = 0; i < 4; ++i) {
        int col = skq * 4;
        pz[i]  = *(const float4*)(W + (size_t)aidx[i] * D + col);
        pxv[i] = *(const float4*)(X + (size_t)(rowBase + srow + i * 32) * D + col);
    }
#pragma unroll
    for (int i = 0; i < 4; ++i) {
        const float* bp = B + (size_t)((sdq + i * 2) * 4) * D + nBase + sn;
        pbv[i] = {bp[0], bp[D], bp[2 * D], bp[3 * D]};
    }

    for (int kc = 0; kc < 32; ++kc) {
        const int bsel = kc & 1;
#pragma unroll
        for (int i = 0; i < 4; ++i) {
            int row = srow + i * 32;
            int col = kc * 32 + skq * 4;
            float4 z = pz[i], xv = pxv[i];
            float4 g  = *(const float4*)&Gs[col];
            float4 bb = *(const float4*)&Bt[col];
            float4 a;
            a.x = (((z.x - xv.x) + xv.x) - amu[i]) * ars[i] * g.x + bb.x;
            a.y = (((z.y - xv.y) + xv.y) - amu[i]) * ars[i] * g.y + bb.y;
            a.z = (((z.z - xv.z) + xv.z) - amu[i]) * ars[i] * g.z + bb.z;
            a.w = (((z.w - xv.w) + xv.w) - amu[i]) * ars[i] * g.w + bb.w;
            uint2 hw, lw;
            split4(a, hw, lw);
            int tile = row >> 4;
            int lf = (row & 15) | ((skq >> 1) << 4);
            int j0 = (skq & 1) * 4;
            *(uint2*)&Ah[bsel][tile][lf][j0] = hw;
            *(uint2*)&Al[bsel][tile][lf][j0] = lw;
        }
#pragma unroll
        for (int i = 0; i < 4; ++i) {
            int dq = sdq + i * 2;
            uint2 hw, lw;
            split4(pbv[i], hw, lw);
            int tile = sn >> 4;
            int lf = (sn & 15) | ((dq >> 1) << 4);
            int j0 = (dq & 1) * 4;
            *(uint2*)&Bh2[bsel][tile][lf][j0] = hw;
            *(uint2*)&Bl2[bsel][tile][lf][j0] = lw;
        }
        __syncthreads();
        float4 pzn[4], pxvn[4], pbvn[4];
        if (kc < 31) {
#pragma unroll
            for (int i = 0; i < 4; ++i) {
                int col = (kc + 1) * 32 + skq * 4;
                pzn[i]  = *(const float4*)(W + (size_t)aidx[i] * D + col);
                pxvn[i] = *(const float4*)(X + (size_t)(rowBase + srow + i * 32) * D + col);
            }
#pragma unroll
            for (int i = 0; i < 4; ++i) {
                const float* bp = B + (size_t)((kc + 1) * 32 + (sdq + i * 2) * 4) * D + nBase + sn;
                pbvn[i] = {bp[0], bp[D], bp[2 * D], bp[3 * D]};
            }
        }
        bf16x8 fah[4], fal[4];
#pragma unroll
        for (int mt = 0; mt < 4; ++mt) {
            fah[mt] = *(const bf16x8*)&Ah[bsel][wy * 4 + mt][l][0];
            fal[mt] = *(const bf16x8*)&Al[bsel][wy * 4 + mt][l][0];
        }
#pragma unroll
        for (int nt = 0; nt < 4; ++nt) {
            bf16x8 bh = *(const bf16x8*)&Bh2[bsel][wx * 4 + nt][l][0];
            bf16x8 bl = *(const bf16x8*)&Bl2[bsel][wx * 4 + nt][l][0];
#pragma unroll
            for (int mt = 0; mt < 4; ++mt) {
                acc[mt][nt] = __builtin_amdgcn_mfma_f32_16x16x32_bf16(fah[mt], bh, acc[mt][nt], 0, 0, 0);
                acc[mt][nt] = __builtin_amdgcn_mfma_f32_16x16x32_bf16(fah[mt], bl, acc[mt][nt], 0, 0, 0);
                acc[mt][nt] = __builtin_amdgcn_mfma_f32_16x16x32_bf16(fal[mt], bh, acc[mt][nt], 0, 0, 0);
            }
        }
        if (kc < 31) {
#pragma unroll
            for (int i = 0; i < 4; ++i) {
                pz[i] = pzn[i]; pxv[i] = pxvn[i]; pbv[i] = pbvn[i];
            }
        }
    }

    const int q = l >> 4, c = l & 15;
#pragma unroll
    for (int mt = 0; mt < 4; ++mt)
#pragma unroll
        for (int nt = 0; nt < 4; ++nt)
#pragma unroll
            for (int r = 0; r < 4; ++r) {
                int grow = rowBase + wy * 64 + mt * 16 + q * 4 + r;
                int gcol = nBase + wx * 64 + nt * 16 + c;
                Out[(size_t)grow * D + gcol] = acc[mt][nt][r];
            }
}

extern "C" void kernel_launch(void* const* d_in, const int* in_sizes, int n_in,
                              void* d_out, int out_size, void* d_ws, size_t ws_size,
                              hipStream_t stream) {
    const float* X     = (const float*)d_in[0];
    const float* W     = (const float*)d_in[1];
    const float* gamma = (const float*)d_in[2];
    const float* beta  = (const float*)d_in[3];
    const float* OW    = (const float*)d_in[4];

    float* out    = (float*)d_out;
    float* outIdx = out;
    float* outSim = out + NROWS;
    float* outO   = out + 2 * NROWS;

    // scratch carved from the 32 MB outO region (all consumed before gemm2 writes it):
    //   Xhi 16 MB | Wfrag 12 MB (per-chunk, reused) | candCol u16 2 MB | count 32 KB
    ushort* Xhi   = (ushort*)outO;
    ushort* Wfrag = Xhi + (size_t)NROWS * D;                    // 12 MB = 6144 rows max
    ushort* candCol = Wfrag + (size_t)6144 * D;
    unsigned int* count = (unsigned int*)(candCol + (size_t)NROWS * NCAND);

    // workspace — ~320 KB
    unsigned long long* packed = (unsigned long long*)d_ws;
    float* RK     = (float*)(packed + NROWS);
    float* RQ     = RK + V;
    float* MU     = RQ + NROWS;
    float* RS     = MU + NROWS;
    int*   idxArr = (int*)(RS + NROWS);

    hipLaunchKernelGGL(prep_kernel, dim3((V + NROWS) / 4), dim3(256), 0, stream,
                       W, X, RK, RQ, packed, count);
    hipLaunchKernelGGL(pack_kernel, dim3(NROWS), dim3(256), 0, stream, X, Xhi);

    // W chunks: 6144, 6144, 4096 codebook rows
    const int chunkRows[3] = {6144, 6144, 4096};
    int colBase = 0;
    for (int ch = 0; ch < 3; ++ch) {
        int rows = chunkRows[ch];
        int perX = (rows / 256) / 8;   // 256-col tiles per XCD: 3, 3, 2
        hipLaunchKernelGGL(pack_kernel, dim3(rows), dim3(256), 0, stream,
                           W + (size_t)colBase * D, Wfrag);
        hipLaunchKernelGGL(gemm1_kernel, dim3((NROWS / 256) * (rows / 256)), dim3(512), 0, stream,
                           Xhi, Wfrag, RK, packed, count, candCol, colBase, perX);
        colBase += rows;
    }

    hipLaunchKernelGGL(rescore_kernel, dim3(NROWS / 4), dim3(256), 0, stream,
                       X, W, RK, RQ, count, candCol, outIdx, outSim, idxArr, MU, RS);
    hipLaunchKernelGGL(gemm2_kernel, dim3(D / 128, NROWS / 128), dim3(256), 0, stream,
                       X, W, idxArr, MU, RS, gamma, beta, OW, outO);
}

// Round 2
// 629.035 us; speedup vs baseline: 1.0486x; 1.0486x over previous
//
#include <hip/hip_runtime.h>
#include <math.h>

#define D 1024
#define V 16384
#define NROWS 8192
#define NCAND 128
#define DELTA 0.03f

typedef __bf16 bf16_t;
typedef bf16_t bf16x8 __attribute__((ext_vector_type(8)));
typedef float f32x4 __attribute__((ext_vector_type(4)));

__device__ __forceinline__ unsigned int sortable_key(float v) {
    unsigned int b = __float_as_uint(v);
    return (b & 0x80000000u) ? ~b : (b | 0x80000000u);
}
__device__ __forceinline__ float unkey(unsigned int key) {
    unsigned int b = (key & 0x80000000u) ? (key & 0x7FFFFFFFu) : ~key;
    return __uint_as_float(b);
}
__device__ __forceinline__ uint2 trunc4(float4 v) {
    unsigned int u0 = __float_as_uint(v.x), u1 = __float_as_uint(v.y);
    unsigned int u2 = __float_as_uint(v.z), u3 = __float_as_uint(v.w);
    uint2 hw;
    hw.x = (u0 >> 16) | (u1 & 0xFFFF0000u);
    hw.y = (u2 >> 16) | (u3 & 0xFFFF0000u);
    return hw;
}
__device__ __forceinline__ void split4(float4 v, uint2& hw, uint2& lw) {
    unsigned int u0 = __float_as_uint(v.x), u1 = __float_as_uint(v.y);
    unsigned int u2 = __float_as_uint(v.z), u3 = __float_as_uint(v.w);
    float l0 = v.x - __uint_as_float(u0 & 0xFFFF0000u);
    float l1 = v.y - __uint_as_float(u1 & 0xFFFF0000u);
    float l2 = v.z - __uint_as_float(u2 & 0xFFFF0000u);
    float l3 = v.w - __uint_as_float(u3 & 0xFFFF0000u);
    hw.x = (u0 >> 16) | (u1 & 0xFFFF0000u);
    hw.y = (u2 >> 16) | (u3 & 0xFFFF0000u);
    lw.x = (__float_as_uint(l0) >> 16) | (__float_as_uint(l1) & 0xFFFF0000u);
    lw.y = (__float_as_uint(l2) >> 16) | (__float_as_uint(l3) & 0xFFFF0000u);
}

// async 16B global->LDS copy (per-lane global addr, wave-uniform LDS base + lane*16)
__device__ __forceinline__ void gload16(const ushort* g, ushort* s) {
    __builtin_amdgcn_global_load_lds((const __attribute__((address_space(1))) void*)g,
                                     (__attribute__((address_space(3))) void*)s,
                                     16, 0, 0);
}

// ---------------- merged: row L2-norms of W and X + zero of packed/count ----------------
__global__ __launch_bounds__(256) void prep_kernel(const float* __restrict__ W,
                                                   const float* __restrict__ X,
                                                   float* __restrict__ RK,
                                                   float* __restrict__ RQ,
                                                   unsigned long long* __restrict__ packed,
                                                   unsigned int* __restrict__ count) {
    int tid = threadIdx.x;
    int row = blockIdx.x * 4 + (tid >> 6);
    int lane = tid & 63;
    const float* src;
    float* dst;
    if (row < V) { src = W + (size_t)row * D; dst = RK + row; }
    else { src = X + (size_t)(row - V) * D; dst = RQ + (row - V); }
    const float4* p = (const float4*)src;
    float ss = 0.f;
#pragma unroll
    for (int i = 0; i < 4; ++i) {
        float4 v = p[lane + 64 * i];
        ss += v.x * v.x + v.y * v.y + v.z * v.z + v.w * v.w;
    }
#pragma unroll
    for (int m = 32; m >= 1; m >>= 1) ss += __shfl_xor(ss, m, 64);
    if (lane == 0) {
        *dst = rsqrtf(fmaxf(ss, 1e-12f));
        if (row >= V) { packed[row - V] = 0ull; count[row - V] = 0u; }
    }
}

// ---------------- truncate rows of src into MFMA-fragment-packed bf16 ----------------
// dst[((t16*32 + kc)*64 + lane)*8 + j]: t16=row>>4, lane=(row&15)|((kk>>3)<<4), j=kk&7 (kk=k&31)
__global__ __launch_bounds__(256) void pack_kernel(const float* __restrict__ src,
                                                   ushort* __restrict__ dst) {
    int f = blockIdx.x * 256 + threadIdx.x;
    int row = f >> 8;
    int kq = f & 255;
    int k0 = kq * 4;
    float4 v = *((const float4*)(src + (size_t)row * D) + kq);
    uint2 hw = trunc4(v);
    int t16 = row >> 4, m = row & 15;
    int kc = k0 >> 5, kk = k0 & 31;
    int lane = m | ((kk >> 3) << 4);
    int j0 = kk & 4;
    int idx = ((t16 * 32 + kc) * 64 + lane) * 8 + j0;
    *(uint2*)(dst + idx) = hw;
}

// ---------------- approx sim GEMM: 256x256 tile, BK=32, 4-deep LDS ring, counted vmcnt ----------------
// 8 waves (2M x 4N), per-wave 128x64 out. K-tile = 32 (1 kc frag). LDS = 4 x 32KB ring slots.
// Per K-tile each wave stages 4x1KB frag units (issued BEFORE the MFMA cluster); the end-of-tile
// vmcnt(8) waits only for tile kt+1, whose loads were issued TWO iterations (~2600+ cyc) earlier.
// vmcnt never drains below 8 in the main loop (tail: 8 -> 4 -> 0).  Fragment-packed global layout
// keeps global_load_lds dests linear (wave-uniform base + lane*16) and ds_read_b128 conflict-free.
__global__ __launch_bounds__(512, 2) void gemm1_kernel(const ushort* __restrict__ Xhi,
                                                       const ushort* __restrict__ Wfrag,
                                                       const float* __restrict__ RK,
                                                       unsigned long long* __restrict__ packed,
                                                       unsigned int* __restrict__ count,
                                                       ushort* __restrict__ candCol,
                                                       int colBase, int perX) {
    __shared__ __align__(16) unsigned char ldsraw[131072];
    ushort* lds = (ushort*)ldsraw;

    const int tid = threadIdx.x;
    const int l = tid & 63;
    const int w = tid >> 6;                 // 0..7
    const int wy = w >> 2, wx = w & 3;      // per-wave: rows wy*128.., cols wx*64..

    const int lin = blockIdx.x;
    const int x = lin & 7;                  // XCD
    const int j = lin >> 3;
    const int rt = j / perX;
    const int ctl = x * perX + (j - rt * perX);
    const int rowBase = rt * 256;
    const int cwLocal = ctl * 256;

    f32x4 acc[8][4];
#pragma unroll
    for (int mt = 0; mt < 8; ++mt)
#pragma unroll
        for (int nt = 0; nt < 4; ++nt) acc[mt][nt] = (f32x4)0.f;

    // staging roles: waves 0-3 stage A (16 units of 1KB), waves 4-7 stage B (16 units).
    // A K-tile (BK=32) slot: A units u=0..15 at u*512, B units at 8192 + u*512  (elements).
    const ushort* gs = (w < 4)
        ? (Xhi + (size_t)(rt * 16 + w * 4) * 16384 + l * 8)
        : (Wfrag + (size_t)(ctl * 16 + (w - 4) * 4) * 16384 + l * 8);
    const int ldsU = (w < 4) ? (w * 4 * 512) : (8192 + (w - 4) * 4 * 512);

    auto stage = [&](int slot, int kt) {
#pragma unroll
        for (int i = 0; i < 4; ++i)
            gload16(gs + (size_t)kt * 512 + i * 16384,
                    lds + slot * 16384 + ldsU + i * 512);
    };

    // prologue: tiles 0,1,2 in flight; wait only for tile 0 (8 newest stay outstanding)
    stage(0, 0);
    stage(1, 1);
    stage(2, 2);
    asm volatile("s_waitcnt vmcnt(8)" ::: "memory");
    __builtin_amdgcn_sched_barrier(0);
    __builtin_amdgcn_s_barrier();

    for (int kt = 0; kt < 32; ++kt) {
        const int base = (kt & 3) * 16384;
        bf16x8 bf[4];
#pragma unroll
        for (int nt = 0; nt < 4; ++nt)
            bf[nt] = *(const bf16x8*)&lds[base + 8192 + (wx * 4 + nt) * 512 + l * 8];
        bf16x8 af[8];
#pragma unroll
        for (int mt = 0; mt < 8; ++mt)
            af[mt] = *(const bf16x8*)&lds[base + (wy * 8 + mt) * 512 + l * 8];
        // issue next-next-next tile's stage EARLY so it overlaps this tile's MFMA cluster;
        // it writes slot (kt+3)&3 == (kt-1)&3, which all waves finished reading last iteration.
        if (kt + 3 < 32) stage((kt + 3) & 3, kt + 3);
        __builtin_amdgcn_s_setprio(1);
#pragma unroll
        for (int nt = 0; nt < 4; ++nt)
#pragma unroll
            for (int mt = 0; mt < 8; ++mt)
                acc[mt][nt] = __builtin_amdgcn_mfma_f32_16x16x32_bf16(af[mt], bf[nt], acc[mt][nt], 0, 0, 0);
        __builtin_amdgcn_s_setprio(0);
        __builtin_amdgcn_s_barrier();           // all waves done reading slot kt&3
        if (kt + 3 < 32) {
            asm volatile("s_waitcnt vmcnt(8)" ::: "memory");   // tile kt+1 landed (issued 2 iters ago)
        } else if (kt == 29) {
            asm volatile("s_waitcnt vmcnt(4)" ::: "memory");   // tile 30 landed
        } else if (kt == 30) {
            asm volatile("s_waitcnt vmcnt(0)" ::: "memory");   // tile 31 landed
        }
        __builtin_amdgcn_sched_barrier(0);
        __builtin_amdgcn_s_barrier();           // tile kt+1 visible to all waves
    }

    // ---- epilogue stage 1: block-level per-row max -> global running max ----
    // staging buffers dead; overlay reduction arrays on LDS.
    unsigned long long (*red)[4] = (unsigned long long (*)[4])ldsraw;   // 256 x 4 x 8B = 8KB
    float* gthr = (float*)(ldsraw + 16384);                             // 1KB @ 16KB

    const int q = l >> 4, c = l & 15;
    float rk_l[4];
#pragma unroll
    for (int nt = 0; nt < 4; ++nt) rk_l[nt] = RK[colBase + cwLocal + wx * 64 + nt * 16 + c];
#pragma unroll
    for (int mt = 0; mt < 8; ++mt) {
#pragma unroll
        for (int r = 0; r < 4; ++r) {
            unsigned long long pk = 0;
#pragma unroll
            for (int nt = 0; nt < 4; ++nt) {
                float v = acc[mt][nt][r] * rk_l[nt];
                int col = colBase + cwLocal + wx * 64 + nt * 16 + c;
                unsigned long long p = ((unsigned long long)sortable_key(v) << 32) |
                                       (unsigned long long)(~(unsigned int)col);
                if (p > pk) pk = p;
            }
#pragma unroll
            for (int m = 1; m < 16; m <<= 1) {
                unsigned long long o = __shfl_xor(pk, m, 64);
                if (o > pk) pk = o;
            }
            if (c == 0) red[wy * 128 + mt * 16 + q * 4 + r][wx] = pk;
        }
    }
    __syncthreads();
    if (tid < 256) {
        unsigned long long a = red[tid][0];
#pragma unroll
        for (int i = 1; i < 4; ++i) { unsigned long long bb = red[tid][i]; if (bb > a) a = bb; }
        unsigned long long old = atomicMax(packed + (rowBase + tid), a);
        unsigned long long g = (old > a) ? old : a;
        gthr[tid] = unkey((unsigned int)(g >> 32)) - DELTA;
    }
    __syncthreads();
    // ---- epilogue stage 2: append candidates within DELTA of known running max ----
#pragma unroll
    for (int mt = 0; mt < 8; ++mt) {
#pragma unroll
        for (int r = 0; r < 4; ++r) {
            int lrow = wy * 128 + mt * 16 + q * 4 + r;
            float thr = gthr[lrow];
            int grow = rowBase + lrow;
#pragma unroll
            for (int nt = 0; nt < 4; ++nt) {
                float v = acc[mt][nt][r] * rk_l[nt];
                if (v >= thr) {
                    unsigned int slot = atomicAdd(count + grow, 1u);
                    if (slot < NCAND) {
                        int col = colBase + cwLocal + wx * 64 + nt * 16 + c;
                        candCol[(size_t)grow * NCAND + slot] = (ushort)col;
                    }
                }
            }
        }
    }
}

// ---------------- exact fp32 rescore + LN stats (merged) ----------------
__global__ __launch_bounds__(256) void rescore_kernel(const float* __restrict__ X,
                                                      const float* __restrict__ W,
                                                      const float* __restrict__ RK,
                                                      const float* __restrict__ RQ,
                                                      const unsigned int* __restrict__ count,
                                                      const ushort* __restrict__ candCol,
                                                      float* __restrict__ outIdx,
                                                      float* __restrict__ outSim,
                                                      int* __restrict__ idxArr,
                                                      float* __restrict__ MU,
                                                      float* __restrict__ RS) {
    int wave = threadIdx.x >> 6, l = threadIdx.x & 63;
    int row = blockIdx.x * 4 + wave;
    unsigned int n = count[row];
    if (n > NCAND) n = NCAND;
    const float4* X4 = (const float4*)X + (size_t)row * 256;
    unsigned long long best = 0;
    for (unsigned int i = 0; i < n; ++i) {
        int col = (int)candCol[(size_t)row * NCAND + i];
        const float4* W4 = (const float4*)W + (size_t)col * 256;
        float s = 0.f;
#pragma unroll
        for (int jj = 0; jj < 4; ++jj) {
            float4 a = X4[jj * 64 + l];
            float4 b = W4[jj * 64 + l];
            s += a.x * b.x + a.y * b.y + a.z * b.z + a.w * b.w;
        }
#pragma unroll
        for (int m = 32; m >= 1; m >>= 1) s += __shfl_xor(s, m, 64);
        float v = s * RK[col];
        unsigned long long pk = ((unsigned long long)sortable_key(v) << 32) |
                                (unsigned long long)(~(unsigned int)col);
        if (pk > best) best = pk;
    }
    int idx = (int)(~(unsigned int)(best & 0xFFFFFFFFull)) & 0xFFFF;
    const float4* Z4 = (const float4*)W + (size_t)idx * 256;
    float s = 0.f, s2 = 0.f;
#pragma unroll
    for (int jj = 0; jj < 4; ++jj) {
        float4 a = X4[jj * 64 + l];
        float4 z = Z4[jj * 64 + l];
        float4 e;
        e.x = (z.x - a.x) + a.x;
        e.y = (z.y - a.y) + a.y;
        e.z = (z.z - a.z) + a.z;
        e.w = (z.w - a.w) + a.w;
        s  += e.x + e.y + e.z + e.w;
        s2 += e.x * e.x + e.y * e.y + e.z * e.z + e.w * e.w;
    }
#pragma unroll
    for (int m = 32; m >= 1; m >>= 1) {
        s  += __shfl_xor(s, m, 64);
        s2 += __shfl_xor(s2, m, 64);
    }
    if (l == 0) {
        outIdx[row] = (float)idx;
        outSim[row] = unkey((unsigned int)(best >> 32)) * RQ[row];
        idxArr[row] = idx;
        float mean = s * (1.f / D);
        float var  = s2 * (1.f / D) - mean * mean;
        MU[row] = mean;
        RS[row] = rsqrtf(var + 1e-6f);
    }
}

// ---------------- projection GEMM: bf16 3-pass MFMA, LN fused into A staging ----------------
__global__ __launch_bounds__(256, 2) void gemm2_kernel(const float* __restrict__ X,
                                                       const float* __restrict__ W,
                                                       const int* __restrict__ idxArr,
                                                       const float* __restrict__ MU,
                                                       const float* __restrict__ RS,
                                                       const float* __restrict__ gamma,
                                                       const float* __restrict__ beta,
                                                       const float* __restrict__ B,
                                                       float* __restrict__ Out) {
    __shared__ ushort Ah[2][8][64][8];
    __shared__ ushort Al[2][8][64][8];
    __shared__ ushort Bh2[2][8][64][8];
    __shared__ ushort Bl2[2][8][64][8];
    __shared__ float Gs[1024];
    __shared__ float Bt[1024];

    const int tid = threadIdx.x;
    const int l = tid & 63;
    const int wave = tid >> 6;
    const int wy = wave >> 1, wx = wave & 1;
    const int rowBase = blockIdx.y * 128;
    const int nBase   = blockIdx.x * 128;

    *(float4*)&Gs[tid * 4] = *(const float4*)(gamma + tid * 4);
    *(float4*)&Bt[tid * 4] = *(const float4*)(beta + tid * 4);

    f32x4 acc[4][4];
#pragma unroll
    for (int mt = 0; mt < 4; ++mt)
#pragma unroll
        for (int nt = 0; nt < 4; ++nt) acc[mt][nt] = (f32x4)0.f;

    const int srow = tid >> 3, skq = tid & 7;
    const int sn = tid & 127, sdq = tid >> 7;
    int aidx[4];
    float amu[4], ars[4];
#pragma unroll
    for (int i = 0; i < 4; ++i) {
        int grow = rowBase + srow + i * 32;
        aidx[i] = idxArr[grow];
        amu[i] = MU[grow];
        ars[i] = RS[grow];
    }

    __syncthreads();

    float4 pz[4], pxv[4], pbv[4];
#pragma unroll
    for (int i = 0; i < 4; ++i) {
        int col = skq * 4;
        pz[i]  = *(const float4*)(W + (size_t)aidx[i] * D + col);
        pxv[i] = *(const float4*)(X + (size_t)(rowBase + srow + i * 32) * D + col);
    }
#pragma unroll
    for (int i = 0; i < 4; ++i) {
        const float* bp = B + (size_t)((sdq + i * 2) * 4) * D + nBase + sn;
        pbv[i] = {bp[0], bp[D], bp[2 * D], bp[3 * D]};
    }

    for (int kc = 0; kc < 32; ++kc) {
        const int bsel = kc & 1;
#pragma unroll
        for (int i = 0; i < 4; ++i) {
            int row = srow + i * 32;
            int col = kc * 32 + skq * 4;
            float4 z = pz[i], xv = pxv[i];
            float4 g  = *(const float4*)&Gs[col];
            float4 bb = *(const float4*)&Bt[col];
            float4 a;
            a.x = (((z.x - xv.x) + xv.x) - amu[i]) * ars[i] * g.x + bb.x;
            a.y = (((z.y - xv.y) + xv.y) - amu[i]) * ars[i] * g.y + bb.y;
            a.z = (((z.z - xv.z) + xv.z) - amu[i]) * ars[i] * g.z + bb.z;
            a.w = (((z.w - xv.w) + xv.w) - amu[i]) * ars[i] * g.w + bb.w;
            uint2 hw, lw;
            split4(a, hw, lw);
            int tile = row >> 4;
            int lf = (row & 15) | ((skq >> 1) << 4);
            int j0 = (skq & 1) * 4;
            *(uint2*)&Ah[bsel][tile][lf][j0] = hw;
            *(uint2*)&Al[bsel][tile][lf][j0] = lw;
        }
#pragma unroll
        for (int i = 0; i < 4; ++i) {
            int dq = sdq + i * 2;
            uint2 hw, lw;
            split4(pbv[i], hw, lw);
            int tile = sn >> 4;
            int lf = (sn & 15) | ((dq >> 1) << 4);
            int j0 = (dq & 1) * 4;
            *(uint2*)&Bh2[bsel][tile][lf][j0] = hw;
            *(uint2*)&Bl2[bsel][tile][lf][j0] = lw;
        }
        __syncthreads();
        float4 pzn[4], pxvn[4], pbvn[4];
        if (kc < 31) {
#pragma unroll
            for (int i = 0; i < 4; ++i) {
                int col = (kc + 1) * 32 + skq * 4;
                pzn[i]  = *(const float4*)(W + (size_t)aidx[i] * D + col);
                pxvn[i] = *(const float4*)(X + (size_t)(rowBase + srow + i * 32) * D + col);
            }
#pragma unroll
            for (int i = 0; i < 4; ++i) {
                const float* bp = B + (size_t)((kc + 1) * 32 + (sdq + i * 2) * 4) * D + nBase + sn;
                pbvn[i] = {bp[0], bp[D], bp[2 * D], bp[3 * D]};
            }
        }
        bf16x8 fah[4], fal[4];
#pragma unroll
        for (int mt = 0; mt < 4; ++mt) {
            fah[mt] = *(const bf16x8*)&Ah[bsel][wy * 4 + mt][l][0];
            fal[mt] = *(const bf16x8*)&Al[bsel][wy * 4 + mt][l][0];
        }
#pragma unroll
        for (int nt = 0; nt < 4; ++nt) {
            bf16x8 bh = *(const bf16x8*)&Bh2[bsel][wx * 4 + nt][l][0];
            bf16x8 bl = *(const bf16x8*)&Bl2[bsel][wx * 4 + nt][l][0];
#pragma unroll
            for (int mt = 0; mt < 4; ++mt) {
                acc[mt][nt] = __builtin_amdgcn_mfma_f32_16x16x32_bf16(fah[mt], bh, acc[mt][nt], 0, 0, 0);
                acc[mt][nt] = __builtin_amdgcn_mfma_f32_16x16x32_bf16(fah[mt], bl, acc[mt][nt], 0, 0, 0);
                acc[mt][nt] = __builtin_amdgcn_mfma_f32_16x16x32_bf16(fal[mt], bh, acc[mt][nt], 0, 0, 0);
            }
        }
        if (kc < 31) {
#pragma unroll
            for (int i = 0; i < 4; ++i) {
                pz[i] = pzn[i]; pxv[i] = pxvn[i]; pbv[i] = pbvn[i];
            }
        }
    }

    const int q = l >> 4, c = l & 15;
#pragma unroll
    for (int mt = 0; mt < 4; ++mt)
#pragma unroll
        for (int nt = 0; nt < 4; ++nt)
#pragma unroll
            for (int r = 0; r < 4; ++r) {
                int grow = rowBase + wy * 64 + mt * 16 + q * 4 + r;
                int gcol = nBase + wx * 64 + nt * 16 + c;
                Out[(size_t)grow * D + gcol] = acc[mt][nt][r];
            }
}

extern "C" void kernel_launch(void* const* d_in, const int* in_sizes, int n_in,
                              void* d_out, int out_size, void* d_ws, size_t ws_size,
                              hipStream_t stream) {
    const float* X     = (const float*)d_in[0];
    const float* W     = (const float*)d_in[1];
    const float* gamma = (const float*)d_in[2];
    const float* beta  = (const float*)d_in[3];
    const float* OW    = (const float*)d_in[4];

    float* out    = (float*)d_out;
    float* outIdx = out;
    float* outSim = out + NROWS;
    float* outO   = out + 2 * NROWS;

    // scratch carved from the 32 MB outO region (all consumed before gemm2 writes it):
    //   Xhi 16 MB | Wfrag 12 MB (per-chunk, reused) | candCol u16 2 MB | count 32 KB
    ushort* Xhi   = (ushort*)outO;
    ushort* Wfrag = Xhi + (size_t)NROWS * D;                    // 12 MB = 6144 rows max
    ushort* candCol = Wfrag + (size_t)6144 * D;
    unsigned int* count = (unsigned int*)(candCol + (size_t)NROWS * NCAND);

    // workspace — ~320 KB
    unsigned long long* packed = (unsigned long long*)d_ws;
    float* RK     = (float*)(packed + NROWS);
    float* RQ     = RK + V;
    float* MU     = RQ + NROWS;
    float* RS     = MU + NROWS;
    int*   idxArr = (int*)(RS + NROWS);

    hipLaunchKernelGGL(prep_kernel, dim3((V + NROWS) / 4), dim3(256), 0, stream,
                       W, X, RK, RQ, packed, count);
    hipLaunchKernelGGL(pack_kernel, dim3(NROWS), dim3(256), 0, stream, X, Xhi);

    // W chunks: 6144, 6144, 4096 codebook rows
    const int chunkRows[3] = {6144, 6144, 4096};
    int colBase = 0;
    for (int ch = 0; ch < 3; ++ch) {
        int rows = chunkRows[ch];
        int perX = (rows / 256) / 8;   // 256-col tiles per XCD: 3, 3, 2
        hipLaunchKernelGGL(pack_kernel, dim3(rows), dim3(256), 0, stream,
                           W + (size_t)colBase * D, Wfrag);
        hipLaunchKernelGGL(gemm1_kernel, dim3((NROWS / 256) * (rows / 256)), dim3(512), 0, stream,
                           Xhi, Wfrag, RK, packed, count, candCol, colBase, perX);
        colBase += rows;
    }

    hipLaunchKernelGGL(rescore_kernel, dim3(NROWS / 4), dim3(256), 0, stream,
                       X, W, RK, RQ, count, candCol, outIdx, outSim, idxArr, MU, RS);
    hipLaunchKernelGGL(gemm2_kernel, dim3(D / 128, NROWS / 128), dim3(256), 0, stream,
                       X, W, idxArr, MU, RS, gamma, beta, OW, outO);
}